// Round 14
// baseline (377.003 us; speedup 1.0000x reference)
//
#include <hip/hip_runtime.h>
#include <hip/hip_bf16.h>
#include <math.h>

#define NEG_SLOPE 0.2f

typedef __attribute__((ext_vector_type(8))) short short8;
typedef __attribute__((ext_vector_type(4))) float f32x4;

__device__ __forceinline__ unsigned short f2b(float v){   // f32 -> bf16 RNE
    unsigned int b = __float_as_uint(v);
    return (unsigned short)((b + 0x7FFFu + ((b >> 16) & 1u)) >> 16);
}

// sum across 16-lane group via ds_swizzle (imm pattern, no addr VGPRs)
__device__ __forceinline__ float swz_add16(float p){
    int q;
    q = __builtin_amdgcn_ds_swizzle(__float_as_int(p), 0x041F); p += __int_as_float(q); // xor 1
    q = __builtin_amdgcn_ds_swizzle(__float_as_int(p), 0x081F); p += __int_as_float(q); // xor 2
    q = __builtin_amdgcn_ds_swizzle(__float_as_int(p), 0x101F); p += __int_as_float(q); // xor 4
    q = __builtin_amdgcn_ds_swizzle(__float_as_int(p), 0x201F); p += __int_as_float(q); // xor 8
    return p;
}

// ---------------- CSR build ----------------

__global__ void edge_count(const int* __restrict__ src, const int* __restrict__ dst,
                           int E, int* __restrict__ counts){
    int e = blockIdx.x * blockDim.x + threadIdx.x;
    if (e >= E) return;
    int s = src[e], d = dst[e];
    if (s != d) atomicAdd(&counts[d], 1);
}

__global__ void scan_block(const int* __restrict__ counts, int* __restrict__ offsets,
                           int* __restrict__ blockSums, int N){
    __shared__ int sh[256];
    int t = threadIdx.x;
    int i = blockIdx.x * 256 + t;
    int v = (i < N) ? counts[i] : 0;
    sh[t] = v; __syncthreads();
    for (int off = 1; off < 256; off <<= 1){
        int x = (t >= off) ? sh[t - off] : 0;
        __syncthreads();
        sh[t] += x;
        __syncthreads();
    }
    if (i < N) offsets[i] = sh[t] - v;           // exclusive
    if (t == 255) blockSums[blockIdx.x] = sh[255];
}

__global__ void scan_sums(int* __restrict__ blockSums, int nb){
    __shared__ int sh[256];
    int t = threadIdx.x;
    int v = (t < nb) ? blockSums[t] : 0;
    sh[t] = v; __syncthreads();
    for (int off = 1; off < 256; off <<= 1){
        int x = (t >= off) ? sh[t - off] : 0;
        __syncthreads();
        sh[t] += x;
        __syncthreads();
    }
    if (t < nb) blockSums[t] = sh[t] - v;        // exclusive
}

__global__ void scan_add(int* __restrict__ offsets, int* __restrict__ cursor,
                         const int* __restrict__ blockSums, int N){
    int i = blockIdx.x * 256 + threadIdx.x;
    if (i < N){
        int v = offsets[i] + blockSums[blockIdx.x];
        offsets[i] = v;
        cursor[i]  = v;
    }
}

// scatter writes row BYTE offsets for both table geometries directly.
// NOTE: self-loop edges are skipped, so only E' <= E slots are written;
// the arrays MUST be fully zeroed beforehand (prefetch reads the gap).
__global__ void edge_scatter(const int* __restrict__ src, const int* __restrict__ dst,
                             int E, int* __restrict__ cursor,
                             int* __restrict__ e384, int* __restrict__ e256){
    int e = blockIdx.x * blockDim.x + threadIdx.x;
    if (e >= E) return;
    int s = src[e], d = dst[e];
    if (s != d){
        int pos = atomicAdd(&cursor[d], 1);
        e384[pos] = s * 384;   // HC=192, bf16
        e256[pos] = s * 256;   // HC=128, bf16
    }
}

// ---------------- fused WT build: 3 layers in one dispatch ----------------
__global__ void build_wt_all(const float* __restrict__ Wl0, const float* __restrict__ Wr0,
                             const float* __restrict__ Wl1, const float* __restrict__ Wr1,
                             const float* __restrict__ Wl2, const float* __restrict__ Wr2,
                             unsigned short* __restrict__ WT0,
                             unsigned short* __restrict__ WT1,
                             unsigned short* __restrict__ WT2){
    int i = blockIdx.x * 256 + threadIdx.x;
    if (i < 12288){                       // 384 x 32
        int c = i / 32, k = i - c * 32;
        float v = (c < 192) ? Wl0[(size_t)k * 192 + c] : Wr0[(size_t)k * 192 + (c - 192)];
        WT0[i] = f2b(v);
    } else if (i < 61440){                // 256 x 192
        int j = i - 12288;
        int c = j / 192, k = j - c * 192;
        float v = (c < 128) ? Wl1[(size_t)k * 128 + c] : Wr1[(size_t)k * 128 + (c - 128)];
        WT1[j] = f2b(v);
    } else if (i < 94208){                // 256 x 128
        int j = i - 61440;
        int c = j / 128, k = j - c * 128;
        float v = (c < 128) ? Wl2[(size_t)k * 128 + c] : Wr2[(size_t)k * 128 + (c - 128)];
        WT2[j] = f2b(v);
    }
}

// ---------------- MFMA dual linear ----------------
// LDS union: xs (staging) is dead after the MFMA loop, so the epilogue
// transpose buffer ep aliases it (barrier in between). LDS <= 25.6KB/block.
template<int K, int COLS, int HC, bool INB>
__global__ __launch_bounds__(256)
void mfma_dual_linear(const void* __restrict__ in_,
                      const unsigned short* __restrict__ WT, // COLS x K (bf16)
                      const float* __restrict__ bl, const float* __restrict__ br,
                      unsigned short* __restrict__ xlb,      // N x HC (bf16)
                      float* __restrict__ xr,                // N x HC (f32)
                      int N){
    constexpr int KP = K + 8;
    constexpr int CT = COLS / 64;
    constexpr int XS_BYTES = 64 * KP * 2;
    constexpr int EP_BYTES = 4 * 64 * 20 * 4;
    constexpr int SM_BYTES = XS_BYTES > EP_BYTES ? XS_BYTES : EP_BYTES;
    __shared__ __align__(16) char smem[SM_BYTES];
    unsigned short* xs = (unsigned short*)smem;
    const int tid = threadIdx.x;
    const int row0 = blockIdx.x * 64;

    {
        const int r = tid >> 2, q = tid & 3;
        int gr = row0 + r; if (gr > N - 1) gr = N - 1;
        unsigned short* op = &xs[r * KP + q * (K / 4)];
        if (INB){
            const unsigned short* ip = (const unsigned short*)in_ + (size_t)gr * K + q * (K / 4);
            #pragma unroll
            for (int kk = 0; kk < K / 4; kk += 8)
                *(uint4*)&op[kk] = *(const uint4*)&ip[kk];
        } else {
            const float* ip = (const float*)in_ + (size_t)gr * K + q * (K / 4);
            #pragma unroll
            for (int kk = 0; kk < K / 4; kk += 4){
                float4 v = *(const float4*)&ip[kk];
                ushort4 o;
                o.x = f2b(v.x); o.y = f2b(v.y); o.z = f2b(v.z); o.w = f2b(v.w);
                *(ushort4*)&op[kk] = o;
            }
        }
    }
    __syncthreads();

    const int w = tid >> 6, lane = tid & 63;
    const int lr = lane & 15, lk = (lane >> 4) * 8;

    f32x4 acc[CT][4];
    #pragma unroll
    for (int ct = 0; ct < CT; ++ct){
        int c = (w * CT + ct) * 16 + lr;
        float bv = (c < HC) ? bl[c] : br[c - HC];
        #pragma unroll
        for (int rt = 0; rt < 4; ++rt) acc[ct][rt] = {bv, bv, bv, bv};
    }

    #pragma unroll
    for (int ks = 0; ks < K / 32; ++ks){
        short8 a[4];
        #pragma unroll
        for (int rt = 0; rt < 4; ++rt)
            a[rt] = *(const short8*)&xs[(rt * 16 + lr) * KP + ks * 32 + lk];
        #pragma unroll
        for (int ct = 0; ct < CT; ++ct){
            int c = (w * CT + ct) * 16 + lr;
            short8 b = *(const short8*)&WT[(size_t)c * K + ks * 32 + lk];
            #pragma unroll
            for (int rt = 0; rt < 4; ++rt)
                acc[ct][rt] = __builtin_amdgcn_mfma_f32_16x16x32_bf16(a[rt], b, acc[ct][rt], 0, 0, 0);
        }
    }

    __syncthreads();      // xs dead everywhere before ep aliases it
    float* my = ((float*)smem) + w * (64 * 20);
    const int rb4 = (lane >> 4) * 4;
    #pragma unroll
    for (int ct = 0; ct < CT; ++ct){
        #pragma unroll
        for (int rt = 0; rt < 4; ++rt){
            const int rbase = rt * 16 + rb4;
            #pragma unroll
            for (int r = 0; r < 4; ++r)
                my[(rbase + r) * 20 + lr] = acc[ct][rt][r];
        }
        const int c0 = (w * CT + ct) * 16;
        const bool left = c0 < HC;
        #pragma unroll
        for (int i = 0; i < 4; ++i){
            int chunk = lane + 64 * i;          // 0..255
            int row = chunk >> 2;
            int c4 = (chunk & 3) * 4;
            int grow = row0 + row;
            if (grow < N){
                float4 v = *(float4*)&my[row * 20 + c4];
                if (left){
                    uint2 w2;
                    w2.x = (unsigned)f2b(v.x) | ((unsigned)f2b(v.y) << 16);
                    w2.y = (unsigned)f2b(v.z) | ((unsigned)f2b(v.w) << 16);
                    *(uint2*)&xlb[(size_t)grow * HC + c0 + c4] = w2;
                } else {
                    *(float4*)&xr[(size_t)grow * HC + (c0 - HC) + c4] = v;
                }
            }
        }
    }
}

// ---------------- GATv2 aggregation (head-fused, depth-2 row prefetch) ----------------
// One wave per node; 4 groups x 16 lanes, edges outer, heads inner (unrolled).
// Depth-2 pipeline: rows for iteration i+1 (un) AND i+2 (unn) in flight ->
// 2x the gather MLP per wave vs depth-1 (latency-hiding at ~4 waves/SIMD).
// Online softmax with defer-max (THR=8), ds_swizzle reduction.
// ebyte fully zeroed + 24 pad: max index read = rs+total+10 < E+24.
template<int H, bool MEAN, bool OUTB>
__global__ __launch_bounds__(256)
void gatv2_agg(const unsigned short* __restrict__ xlb, const float* __restrict__ xr,
               const float* __restrict__ att, const float* __restrict__ bias,
               const int* __restrict__ offsets, const int* __restrict__ counts,
               const int* __restrict__ ebyte,
               void* __restrict__ hout, int N){
    const int HC = H * 64;
    const int RB = HC * 2;                 // xlb row bytes
    int n    = (blockIdx.x * 256 + threadIdx.x) >> 6;
    int lane = threadIdx.x & 63;
    int g = lane >> 4, sl = lane & 15, cb = sl * 4;
    if (n >= N) return;
    const int rs = offsets[n];
    const int total = counts[n] + 1;       // + implicit self loop (virtual idx 0)
    const char* XB = (const char*)xlb;
    const unsigned selfb = (unsigned)(n * RB);

    float4 a4[H], q4[H];
    float m[H], den[H], ax[H], ay[H], az[H], aw[H];
    #pragma unroll
    for (int h = 0; h < H; ++h){
        a4[h] = *(const float4*)&att[h * 64 + cb];
        q4[h] = *(const float4*)&xr[(size_t)n * HC + h * 64 + cb];
        m[h] = -INFINITY; den[h] = 0.f;
        ax[h] = 0.f; ay[h] = 0.f; az[h] = 0.f; aw[h] = 0.f;
    }

    int vi = g;
    if (vi < total){
        unsigned boff0 = (g == 0) ? selfb : (unsigned)ebyte[rs + g - 1];
        uint2 u[H], un[H];
        #pragma unroll
        for (int h = 0; h < H; ++h)
            u[h] = *(const uint2*)(XB + (boff0 + (unsigned)((h * 64 + cb) * 2)));
        unsigned boff1 = (unsigned)ebyte[rs + vi + 3];       // edge vi+4 (pad-safe)
        #pragma unroll
        for (int h = 0; h < H; ++h)
            un[h] = *(const uint2*)(XB + (boff1 + (unsigned)((h * 64 + cb) * 2)));
        unsigned boff2 = (unsigned)ebyte[rs + vi + 7];       // edge vi+8 (pad-safe)
        while (vi < total){
            uint2 unn[H];
            #pragma unroll
            for (int h = 0; h < H; ++h)
                unn[h] = *(const uint2*)(XB + (boff2 + (unsigned)((h * 64 + cb) * 2)));
            boff2 = (unsigned)ebyte[rs + vi + 11];           // edge vi+12 (pad-safe)
            #pragma unroll
            for (int h = 0; h < H; ++h){
                float x0 = __uint_as_float(u[h].x << 16);
                float x1 = __uint_as_float(u[h].x & 0xFFFF0000u);
                float x2 = __uint_as_float(u[h].y << 16);
                float x3 = __uint_as_float(u[h].y & 0xFFFF0000u);
                float t0 = q4[h].x + x0, t1 = q4[h].y + x1;
                float t2 = q4[h].z + x2, t3 = q4[h].w + x3;
                t0 = fmaxf(t0, NEG_SLOPE * t0);
                t1 = fmaxf(t1, NEG_SLOPE * t1);
                t2 = fmaxf(t2, NEG_SLOPE * t2);
                t3 = fmaxf(t3, NEG_SLOPE * t3);
                float p = a4[h].x * t0 + a4[h].y * t1 + a4[h].z * t2 + a4[h].w * t3;
                p = swz_add16(p);
                float d = p - m[h];              // first iter: +inf
                if (d > 8.f){                    // rare record jump -> rescale
                    float s = __expf(-d);        // first iter: exp(-inf)=0
                    den[h] *= s; ax[h] *= s; ay[h] *= s; az[h] *= s; aw[h] *= s;
                    m[h] = p; d = 0.f;
                }
                float eb = __expf(d);            // <= e^8, bounded
                den[h] += eb;
                ax[h] += eb * x0; ay[h] += eb * x1;
                az[h] += eb * x2; aw[h] += eb * x3;
                u[h] = un[h]; un[h] = unn[h];
            }
            vi += 4;
        }
    }
    // merge the 4 group states per head (exact for any per-group reference m)
    #pragma unroll
    for (int h = 0; h < H; ++h){
        #pragma unroll
        for (int off = 16; off <= 32; off <<= 1){
            float mo  = __shfl_xor(m[h],  off, 64);
            float dno = __shfl_xor(den[h], off, 64);
            float bx = __shfl_xor(ax[h], off, 64), by = __shfl_xor(ay[h], off, 64);
            float bz = __shfl_xor(az[h], off, 64), bw = __shfl_xor(aw[h], off, 64);
            float Mn = fmaxf(m[h], mo);
            float sa = (m[h] == -INFINITY) ? 0.f : __expf(m[h] - Mn);
            float sb = (mo   == -INFINITY) ? 0.f : __expf(mo   - Mn);
            den[h] = den[h] * sa + dno * sb;
            ax[h] = ax[h] * sa + bx * sb; ay[h] = ay[h] * sa + by * sb;
            az[h] = az[h] * sa + bz * sb; aw[h] = aw[h] * sa + bw * sb;
            m[h] = Mn;
        }
        float inv = 1.f / den[h];                // self loop: den > 0
        ax[h] *= inv; ay[h] *= inv; az[h] *= inv; aw[h] *= inv;
    }
    if (lane < 16){
        if (MEAN){
            float ox = 0.f, oy = 0.f, oz = 0.f, ow = 0.f;
            #pragma unroll
            for (int h = 0; h < H; ++h){ ox += ax[h]; oy += ay[h]; oz += az[h]; ow += aw[h]; }
            const float s = 1.f / H;
            const float4 bv = *(const float4*)&bias[cb];
            float4 o;
            o.x = fmaxf(ox * s + bv.x, 0.f);
            o.y = fmaxf(oy * s + bv.y, 0.f);
            o.z = fmaxf(oz * s + bv.z, 0.f);
            o.w = fmaxf(ow * s + bv.w, 0.f);
            *(float4*)&((float*)hout)[(size_t)n * 64 + cb] = o;
        } else {
            #pragma unroll
            for (int h = 0; h < H; ++h){
                const float4 bv = *(const float4*)&bias[h * 64 + cb];
                float o0 = fmaxf(ax[h] + bv.x, 0.f), o1 = fmaxf(ay[h] + bv.y, 0.f);
                float o2 = fmaxf(az[h] + bv.z, 0.f), o3 = fmaxf(aw[h] + bv.w, 0.f);
                if (OUTB){
                    uint2 w2;
                    w2.x = (unsigned)f2b(o0) | ((unsigned)f2b(o1) << 16);
                    w2.y = (unsigned)f2b(o2) | ((unsigned)f2b(o3) << 16);
                    *(uint2*)&((unsigned short*)hout)[(size_t)n * HC + h * 64 + cb] = w2;
                } else {
                    float4 o; o.x = o0; o.y = o1; o.z = o2; o.w = o3;
                    *(float4*)&((float*)hout)[(size_t)n * HC + h * 64 + cb] = o;
                }
            }
        }
    }
}

// ---------------- pooling (run-length local reduce; batch is sorted) ----------------
__global__ __launch_bounds__(256)
void pool_kernel(const float* __restrict__ h, const int* __restrict__ batch,
                 int N, float* __restrict__ gmx, float* __restrict__ gsum,
                 int* __restrict__ gcnt){
    const int lane = threadIdx.x & 63;
    const int w = threadIdx.x >> 6;
    const int n0 = blockIdx.x * 256;
    const int nend = min(n0 + 256, N);
    float rmax = 0.f, rsum = 0.f;
    int curG = -1, cnt = 0;
    for (int n = n0 + w; n < nend; n += 4){
        int g = batch[n];
        float v = h[(size_t)n * 64 + lane];
        if (g != curG){
            if (curG >= 0){
                atomicMax((int*)&gmx[curG * 64 + lane], __float_as_int(rmax));
                atomicAdd(&gsum[curG * 64 + lane], rsum);
                if (lane == 0) atomicAdd(&gcnt[curG], cnt);
            }
            curG = g; rmax = v; rsum = v; cnt = 1;
        } else {
            rmax = fmaxf(rmax, v); rsum += v; ++cnt;
        }
    }
    if (curG >= 0){
        atomicMax((int*)&gmx[curG * 64 + lane], __float_as_int(rmax));
        atomicAdd(&gsum[curG * 64 + lane], rsum);
        if (lane == 0) atomicAdd(&gcnt[curG], cnt);
    }
}

__global__ __launch_bounds__(640)
void final_linear(const float* __restrict__ gmx, const float* __restrict__ gsum,
                  const int* __restrict__ gcnt,
                  const float* __restrict__ Wout, const float* __restrict__ bout,
                  float* __restrict__ out){
    __shared__ float sg[4096], ss[4096];
    int t = threadIdx.x;
    for (int i = t; i < 4096; i += 640){ sg[i] = gmx[i]; ss[i] = gsum[i]; }
    __syncthreads();
    int g = t / 10, oc = t % 10;
    float icnt = 1.f / (float)max(gcnt[g], 1);
    float acc = bout[oc], accs = 0.f;
    #pragma unroll 4
    for (int k = 0; k < 64; ++k) acc  += sg[g * 64 + k] * Wout[k * 10 + oc];
    #pragma unroll 4
    for (int k = 0; k < 64; ++k) accs += ss[g * 64 + k] * Wout[(64 + k) * 10 + oc];
    out[g * 10 + oc] = acc + accs * icnt;
}

// ---------------- launch ----------------
extern "C" void kernel_launch(void* const* d_in, const int* in_sizes, int n_in,
                              void* d_out, int out_size, void* d_ws, size_t ws_size,
                              hipStream_t stream){
    const int N = 50000, E = 800000, B = 64;
    const float* x    = (const float*)d_in[0];
    const int*  ei    = (const int*)d_in[1];
    const int*  batch = (const int*)d_in[2];
    const float *Wl0=(const float*)d_in[3],  *bl0=(const float*)d_in[4],
                *Wr0=(const float*)d_in[5],  *br0=(const float*)d_in[6],
                *att0=(const float*)d_in[7], *bias0=(const float*)d_in[8];
    const float *Wl1=(const float*)d_in[9],  *bl1=(const float*)d_in[10],
                *Wr1=(const float*)d_in[11], *br1=(const float*)d_in[12],
                *att1=(const float*)d_in[13],*bias1=(const float*)d_in[14];
    const float *Wl2=(const float*)d_in[15], *bl2=(const float*)d_in[16],
                *Wr2=(const float*)d_in[17], *br2=(const float*)d_in[18],
                *att2=(const float*)d_in[19],*bias2=(const float*)d_in[20];
    const float *Wout=(const float*)d_in[21],*bout=(const float*)d_in[22];

    const int* srcA = ei;
    const int* dstA = ei + E;

    char* p = (char*)d_ws;
    auto alloc = [&](size_t bytes)->void*{ void* r = (void*)p; p += (bytes + 255) & ~(size_t)255; return r; };
    void*  bufA   = alloc((size_t)N * 192 * 4);                 // h: bf16 (L0,L1) / f32 (L2)
    float* bufC   = (float*)alloc((size_t)N * 192 * 4);         // xr (f32)
    unsigned short* xlb = (unsigned short*)alloc((size_t)N * 192 * 2); // xl (bf16)
    unsigned short* WT0 = (unsigned short*)alloc((size_t)384 * 32 * 2);
    unsigned short* WT1 = (unsigned short*)alloc((size_t)256 * 192 * 2);
    unsigned short* WT2 = (unsigned short*)alloc((size_t)256 * 128 * 2);
    int* counts   = (int*)alloc((size_t)N * 4);
    int* offsets  = (int*)alloc((size_t)N * 4);
    int* cursor   = (int*)alloc((size_t)N * 4);
    int* blockSums= (int*)alloc(256 * 4);
    int* eb384    = (int*)alloc((size_t)(E + 24) * 4);
    int* eb256    = (int*)alloc((size_t)(E + 24) * 4);
    float* pool   = (float*)alloc((size_t)(B * 128 + B) * 4);   // gmx | gsum | gcnt
    float* gmx  = pool;
    float* gsum = pool + B * 64;
    int*   gcnt = (int*)(pool + B * 128);

    // weight transpose + bf16 (one dispatch)
    build_wt_all<<<(94208 + 255) / 256, 256, 0, stream>>>(Wl0, Wr0, Wl1, Wr1, Wl2, Wr2, WT0, WT1, WT2);

    // CSR build (reused by all 3 layers)
    hipMemsetAsync(counts, 0, (size_t)N * 4, stream);
    // FULL zero of both offset arrays: self-loop edges leave an E'..E gap that
    // the aggregation prefetch reads (r8/r9 fault: 0xAA poison -> OOB deref).
    hipMemsetAsync(eb384, 0, (size_t)(E + 24) * 4, stream);
    hipMemsetAsync(eb256, 0, (size_t)(E + 24) * 4, stream);
    int eb = (E + 255) / 256;
    int nb = (N + 255) / 256;
    edge_count<<<eb, 256, 0, stream>>>(srcA, dstA, E, counts);
    scan_block<<<nb, 256, 0, stream>>>(counts, offsets, blockSums, N);
    scan_sums<<<1, 256, 0, stream>>>(blockSums, nb);
    scan_add<<<nb, 256, 0, stream>>>(offsets, cursor, blockSums, N);
    edge_scatter<<<eb, 256, 0, stream>>>(srcA, dstA, E, cursor, eb384, eb256);

    const int rb = (N + 63) / 64;   // 64-row tiles
    const int ab = (N + 3) / 4;     // agg blocks: one wave per node

    // layer 0: 32 -> 192 (H=3, C=64), concat; h0 out bf16
    mfma_dual_linear<32, 384, 192, false><<<rb, 256, 0, stream>>>(x, WT0, bl0, br0, xlb, bufC, N);
    gatv2_agg<3, false, true><<<ab, 256, 0, stream>>>(xlb, bufC, att0, bias0, offsets, counts, eb384, bufA, N);

    // layer 1: 192 -> 128 (H=2), concat; h1 out bf16
    mfma_dual_linear<192, 256, 128, true><<<rb, 256, 0, stream>>>(bufA, WT1, bl1, br1, xlb, bufC, N);
    gatv2_agg<2, false, true><<<ab, 256, 0, stream>>>(xlb, bufC, att1, bias1, offsets, counts, eb256, bufA, N);

    // layer 2: 128 -> 128 (H=2), mean over heads -> 64; out f32 for pooling
    mfma_dual_linear<128, 256, 128, true><<<rb, 256, 0, stream>>>(bufA, WT2, bl2, br2, xlb, bufC, N);
    gatv2_agg<2, true, false><<<ab, 256, 0, stream>>>(xlb, bufC, att2, bias2, offsets, counts, eb256, bufA, N);

    // pooling + output linear
    hipMemsetAsync(pool, 0, (size_t)(B * 128 + B) * 4, stream);
    pool_kernel<<<(N + 255) / 256, 256, 0, stream>>>((const float*)bufA, batch, N, gmx, gsum, gcnt);
    final_linear<<<1, 640, 0, stream>>>(gmx, gsum, gcnt, Wout, bout, (float*)d_out);
}

// Round 15
// 365.592 us; speedup vs baseline: 1.0312x; 1.0312x over previous
//
#include <hip/hip_runtime.h>
#include <hip/hip_bf16.h>
#include <math.h>

#define NEG_SLOPE 0.2f

typedef __attribute__((ext_vector_type(8))) short short8;
typedef __attribute__((ext_vector_type(4))) float f32x4;

__device__ __forceinline__ unsigned short f2b(float v){   // f32 -> bf16 RNE
    unsigned int b = __float_as_uint(v);
    return (unsigned short)((b + 0x7FFFu + ((b >> 16) & 1u)) >> 16);
}

// sum across 16-lane group via ds_swizzle (imm pattern, no addr VGPRs)
__device__ __forceinline__ float swz_add16(float p){
    int q;
    q = __builtin_amdgcn_ds_swizzle(__float_as_int(p), 0x041F); p += __int_as_float(q); // xor 1
    q = __builtin_amdgcn_ds_swizzle(__float_as_int(p), 0x081F); p += __int_as_float(q); // xor 2
    q = __builtin_amdgcn_ds_swizzle(__float_as_int(p), 0x101F); p += __int_as_float(q); // xor 4
    q = __builtin_amdgcn_ds_swizzle(__float_as_int(p), 0x201F); p += __int_as_float(q); // xor 8
    return p;
}

// ---------------- CSR build ----------------

__global__ void edge_count(const int* __restrict__ src, const int* __restrict__ dst,
                           int E, int* __restrict__ counts){
    int e = blockIdx.x * blockDim.x + threadIdx.x;
    if (e >= E) return;
    int s = src[e], d = dst[e];
    if (s != d) atomicAdd(&counts[d], 1);
}

__global__ void scan_block(const int* __restrict__ counts, int* __restrict__ offsets,
                           int* __restrict__ blockSums, int N){
    __shared__ int sh[256];
    int t = threadIdx.x;
    int i = blockIdx.x * 256 + t;
    int v = (i < N) ? counts[i] : 0;
    sh[t] = v; __syncthreads();
    for (int off = 1; off < 256; off <<= 1){
        int x = (t >= off) ? sh[t - off] : 0;
        __syncthreads();
        sh[t] += x;
        __syncthreads();
    }
    if (i < N) offsets[i] = sh[t] - v;           // exclusive
    if (t == 255) blockSums[blockIdx.x] = sh[255];
}

__global__ void scan_sums(int* __restrict__ blockSums, int nb){
    __shared__ int sh[256];
    int t = threadIdx.x;
    int v = (t < nb) ? blockSums[t] : 0;
    sh[t] = v; __syncthreads();
    for (int off = 1; off < 256; off <<= 1){
        int x = (t >= off) ? sh[t - off] : 0;
        __syncthreads();
        sh[t] += x;
        __syncthreads();
    }
    if (t < nb) blockSums[t] = sh[t] - v;        // exclusive
}

__global__ void scan_add(int* __restrict__ offsets, int* __restrict__ cursor,
                         const int* __restrict__ blockSums, int N){
    int i = blockIdx.x * 256 + threadIdx.x;
    if (i < N){
        int v = offsets[i] + blockSums[blockIdx.x];
        offsets[i] = v;
        cursor[i]  = v;
    }
}

// scatter writes row BYTE offsets for both table geometries directly.
// NOTE: self-loop edges are skipped, so only E' <= E slots are written;
// the arrays MUST be fully zeroed beforehand (prefetch reads the gap).
__global__ void edge_scatter(const int* __restrict__ src, const int* __restrict__ dst,
                             int E, int* __restrict__ cursor,
                             int* __restrict__ e384, int* __restrict__ e256){
    int e = blockIdx.x * blockDim.x + threadIdx.x;
    if (e >= E) return;
    int s = src[e], d = dst[e];
    if (s != d){
        int pos = atomicAdd(&cursor[d], 1);
        e384[pos] = s * 384;   // HC=192, bf16
        e256[pos] = s * 256;   // HC=128, bf16
    }
}

// ---------------- fused WT build: 3 layers in one dispatch ----------------
__global__ void build_wt_all(const float* __restrict__ Wl0, const float* __restrict__ Wr0,
                             const float* __restrict__ Wl1, const float* __restrict__ Wr1,
                             const float* __restrict__ Wl2, const float* __restrict__ Wr2,
                             unsigned short* __restrict__ WT0,
                             unsigned short* __restrict__ WT1,
                             unsigned short* __restrict__ WT2){
    int i = blockIdx.x * 256 + threadIdx.x;
    if (i < 12288){                       // 384 x 32
        int c = i / 32, k = i - c * 32;
        float v = (c < 192) ? Wl0[(size_t)k * 192 + c] : Wr0[(size_t)k * 192 + (c - 192)];
        WT0[i] = f2b(v);
    } else if (i < 61440){                // 256 x 192
        int j = i - 12288;
        int c = j / 192, k = j - c * 192;
        float v = (c < 128) ? Wl1[(size_t)k * 128 + c] : Wr1[(size_t)k * 128 + (c - 128)];
        WT1[j] = f2b(v);
    } else if (i < 94208){                // 256 x 128
        int j = i - 61440;
        int c = j / 128, k = j - c * 128;
        float v = (c < 128) ? Wl2[(size_t)k * 128 + c] : Wr2[(size_t)k * 128 + (c - 128)];
        WT2[j] = f2b(v);
    }
}

// ---------------- MFMA dual linear ----------------
// LDS union: xs (staging) is dead after the MFMA loop, so the epilogue
// transpose buffer ep aliases it (barrier in between). LDS <= 25.6KB/block.
template<int K, int COLS, int HC, bool INB>
__global__ __launch_bounds__(256)
void mfma_dual_linear(const void* __restrict__ in_,
                      const unsigned short* __restrict__ WT, // COLS x K (bf16)
                      const float* __restrict__ bl, const float* __restrict__ br,
                      unsigned short* __restrict__ xlb,      // N x HC (bf16)
                      float* __restrict__ xr,                // N x HC (f32)
                      int N){
    constexpr int KP = K + 8;
    constexpr int CT = COLS / 64;
    constexpr int XS_BYTES = 64 * KP * 2;
    constexpr int EP_BYTES = 4 * 64 * 20 * 4;
    constexpr int SM_BYTES = XS_BYTES > EP_BYTES ? XS_BYTES : EP_BYTES;
    __shared__ __align__(16) char smem[SM_BYTES];
    unsigned short* xs = (unsigned short*)smem;
    const int tid = threadIdx.x;
    const int row0 = blockIdx.x * 64;

    {
        const int r = tid >> 2, q = tid & 3;
        int gr = row0 + r; if (gr > N - 1) gr = N - 1;
        unsigned short* op = &xs[r * KP + q * (K / 4)];
        if (INB){
            const unsigned short* ip = (const unsigned short*)in_ + (size_t)gr * K + q * (K / 4);
            #pragma unroll
            for (int kk = 0; kk < K / 4; kk += 8)
                *(uint4*)&op[kk] = *(const uint4*)&ip[kk];
        } else {
            const float* ip = (const float*)in_ + (size_t)gr * K + q * (K / 4);
            #pragma unroll
            for (int kk = 0; kk < K / 4; kk += 4){
                float4 v = *(const float4*)&ip[kk];
                ushort4 o;
                o.x = f2b(v.x); o.y = f2b(v.y); o.z = f2b(v.z); o.w = f2b(v.w);
                *(ushort4*)&op[kk] = o;
            }
        }
    }
    __syncthreads();

    const int w = tid >> 6, lane = tid & 63;
    const int lr = lane & 15, lk = (lane >> 4) * 8;

    f32x4 acc[CT][4];
    #pragma unroll
    for (int ct = 0; ct < CT; ++ct){
        int c = (w * CT + ct) * 16 + lr;
        float bv = (c < HC) ? bl[c] : br[c - HC];
        #pragma unroll
        for (int rt = 0; rt < 4; ++rt) acc[ct][rt] = {bv, bv, bv, bv};
    }

    #pragma unroll
    for (int ks = 0; ks < K / 32; ++ks){
        short8 a[4];
        #pragma unroll
        for (int rt = 0; rt < 4; ++rt)
            a[rt] = *(const short8*)&xs[(rt * 16 + lr) * KP + ks * 32 + lk];
        #pragma unroll
        for (int ct = 0; ct < CT; ++ct){
            int c = (w * CT + ct) * 16 + lr;
            short8 b = *(const short8*)&WT[(size_t)c * K + ks * 32 + lk];
            #pragma unroll
            for (int rt = 0; rt < 4; ++rt)
                acc[ct][rt] = __builtin_amdgcn_mfma_f32_16x16x32_bf16(a[rt], b, acc[ct][rt], 0, 0, 0);
        }
    }

    __syncthreads();      // xs dead everywhere before ep aliases it
    float* my = ((float*)smem) + w * (64 * 20);
    const int rb4 = (lane >> 4) * 4;
    #pragma unroll
    for (int ct = 0; ct < CT; ++ct){
        #pragma unroll
        for (int rt = 0; rt < 4; ++rt){
            const int rbase = rt * 16 + rb4;
            #pragma unroll
            for (int r = 0; r < 4; ++r)
                my[(rbase + r) * 20 + lr] = acc[ct][rt][r];
        }
        const int c0 = (w * CT + ct) * 16;
        const bool left = c0 < HC;
        #pragma unroll
        for (int i = 0; i < 4; ++i){
            int chunk = lane + 64 * i;          // 0..255
            int row = chunk >> 2;
            int c4 = (chunk & 3) * 4;
            int grow = row0 + row;
            if (grow < N){
                float4 v = *(float4*)&my[row * 20 + c4];
                if (left){
                    uint2 w2;
                    w2.x = (unsigned)f2b(v.x) | ((unsigned)f2b(v.y) << 16);
                    w2.y = (unsigned)f2b(v.z) | ((unsigned)f2b(v.w) << 16);
                    *(uint2*)&xlb[(size_t)grow * HC + c0 + c4] = w2;
                } else {
                    *(float4*)&xr[(size_t)grow * HC + (c0 - HC) + c4] = v;
                }
            }
        }
    }
}

// ---------------- GATv2 aggregation (head-fused: one wave per NODE) ----------------
// 4 groups x 16 lanes, 4 edges in flight; edges outer, heads inner (unrolled,
// compile-time H -> register arrays stay in VGPRs). Index loads + loop control
// amortized across H. Online softmax with defer-max (THR=8), ds_swizzle
// reduction, 2-deep index / 1-deep row prefetch. ebyte fully zeroed, +24 pad
// (max read rs+total+6).
template<int H, bool MEAN, bool OUTB>
__global__ __launch_bounds__(256)
void gatv2_agg(const unsigned short* __restrict__ xlb, const float* __restrict__ xr,
               const float* __restrict__ att, const float* __restrict__ bias,
               const int* __restrict__ offsets, const int* __restrict__ counts,
               const int* __restrict__ ebyte,
               void* __restrict__ hout, int N){
    const int HC = H * 64;
    const int RB = HC * 2;                 // xlb row bytes
    int n    = (blockIdx.x * 256 + threadIdx.x) >> 6;
    int lane = threadIdx.x & 63;
    int g = lane >> 4, sl = lane & 15, cb = sl * 4;
    if (n >= N) return;
    const int rs = offsets[n];
    const int total = counts[n] + 1;       // + implicit self loop (virtual idx 0)
    const char* XB = (const char*)xlb;
    const unsigned selfb = (unsigned)(n * RB);

    float4 a4[H], q4[H];
    float m[H], den[H], ax[H], ay[H], az[H], aw[H];
    #pragma unroll
    for (int h = 0; h < H; ++h){
        a4[h] = *(const float4*)&att[h * 64 + cb];
        q4[h] = *(const float4*)&xr[(size_t)n * HC + h * 64 + cb];
        m[h] = -INFINITY; den[h] = 0.f;
        ax[h] = 0.f; ay[h] = 0.f; az[h] = 0.f; aw[h] = 0.f;
    }

    int vi = g;
    if (vi < total){
        unsigned boff = (g == 0) ? selfb : (unsigned)ebyte[rs + g - 1];
        uint2 u[H];
        #pragma unroll
        for (int h = 0; h < H; ++h)
            u[h] = *(const uint2*)(XB + (boff + (unsigned)((h * 64 + cb) * 2)));
        unsigned boffn = (unsigned)ebyte[rs + vi + 3];       // idx of edge vi+4 (pad-safe)
        while (vi < total){
            int vin = vi + 4;
            uint2 un[H];
            #pragma unroll
            for (int h = 0; h < H; ++h)
                un[h] = *(const uint2*)(XB + (boffn + (unsigned)((h * 64 + cb) * 2)));
            boffn = (unsigned)ebyte[rs + vin + 3];           // idx of edge vi+8 (pad-safe)
            #pragma unroll
            for (int h = 0; h < H; ++h){
                float x0 = __uint_as_float(u[h].x << 16);
                float x1 = __uint_as_float(u[h].x & 0xFFFF0000u);
                float x2 = __uint_as_float(u[h].y << 16);
                float x3 = __uint_as_float(u[h].y & 0xFFFF0000u);
                float t0 = q4[h].x + x0, t1 = q4[h].y + x1;
                float t2 = q4[h].z + x2, t3 = q4[h].w + x3;
                t0 = fmaxf(t0, NEG_SLOPE * t0);
                t1 = fmaxf(t1, NEG_SLOPE * t1);
                t2 = fmaxf(t2, NEG_SLOPE * t2);
                t3 = fmaxf(t3, NEG_SLOPE * t3);
                float p = a4[h].x * t0 + a4[h].y * t1 + a4[h].z * t2 + a4[h].w * t3;
                p = swz_add16(p);
                float d = p - m[h];              // first iter: +inf
                if (d > 8.f){                    // rare record jump -> rescale
                    float s = __expf(-d);        // first iter: exp(-inf)=0
                    den[h] *= s; ax[h] *= s; ay[h] *= s; az[h] *= s; aw[h] *= s;
                    m[h] = p; d = 0.f;
                }
                float eb = __expf(d);            // <= e^8, bounded
                den[h] += eb;
                ax[h] += eb * x0; ay[h] += eb * x1;
                az[h] += eb * x2; aw[h] += eb * x3;
                u[h] = un[h];
            }
            vi = vin;
        }
    }
    // merge the 4 group states per head (exact for any per-group reference m)
    #pragma unroll
    for (int h = 0; h < H; ++h){
        #pragma unroll
        for (int off = 16; off <= 32; off <<= 1){
            float mo  = __shfl_xor(m[h],  off, 64);
            float dno = __shfl_xor(den[h], off, 64);
            float bx = __shfl_xor(ax[h], off, 64), by = __shfl_xor(ay[h], off, 64);
            float bz = __shfl_xor(az[h], off, 64), bw = __shfl_xor(aw[h], off, 64);
            float Mn = fmaxf(m[h], mo);
            float sa = (m[h] == -INFINITY) ? 0.f : __expf(m[h] - Mn);
            float sb = (mo   == -INFINITY) ? 0.f : __expf(mo   - Mn);
            den[h] = den[h] * sa + dno * sb;
            ax[h] = ax[h] * sa + bx * sb; ay[h] = ay[h] * sa + by * sb;
            az[h] = az[h] * sa + bz * sb; aw[h] = aw[h] * sa + bw * sb;
            m[h] = Mn;
        }
        float inv = 1.f / den[h];                // self loop: den > 0
        ax[h] *= inv; ay[h] *= inv; az[h] *= inv; aw[h] *= inv;
    }
    if (lane < 16){
        if (MEAN){
            float ox = 0.f, oy = 0.f, oz = 0.f, ow = 0.f;
            #pragma unroll
            for (int h = 0; h < H; ++h){ ox += ax[h]; oy += ay[h]; oz += az[h]; ow += aw[h]; }
            const float s = 1.f / H;
            const float4 bv = *(const float4*)&bias[cb];
            float4 o;
            o.x = fmaxf(ox * s + bv.x, 0.f);
            o.y = fmaxf(oy * s + bv.y, 0.f);
            o.z = fmaxf(oz * s + bv.z, 0.f);
            o.w = fmaxf(ow * s + bv.w, 0.f);
            *(float4*)&((float*)hout)[(size_t)n * 64 + cb] = o;
        } else {
            #pragma unroll
            for (int h = 0; h < H; ++h){
                const float4 bv = *(const float4*)&bias[h * 64 + cb];
                float o0 = fmaxf(ax[h] + bv.x, 0.f), o1 = fmaxf(ay[h] + bv.y, 0.f);
                float o2 = fmaxf(az[h] + bv.z, 0.f), o3 = fmaxf(aw[h] + bv.w, 0.f);
                if (OUTB){
                    uint2 w2;
                    w2.x = (unsigned)f2b(o0) | ((unsigned)f2b(o1) << 16);
                    w2.y = (unsigned)f2b(o2) | ((unsigned)f2b(o3) << 16);
                    *(uint2*)&((unsigned short*)hout)[(size_t)n * HC + h * 64 + cb] = w2;
                } else {
                    float4 o; o.x = o0; o.y = o1; o.z = o2; o.w = o3;
                    *(float4*)&((float*)hout)[(size_t)n * HC + h * 64 + cb] = o;
                }
            }
        }
    }
}

// ---------------- pooling (run-length local reduce; batch is sorted) ----------------
__global__ __launch_bounds__(256)
void pool_kernel(const float* __restrict__ h, const int* __restrict__ batch,
                 int N, float* __restrict__ gmx, float* __restrict__ gsum,
                 int* __restrict__ gcnt){
    const int lane = threadIdx.x & 63;
    const int w = threadIdx.x >> 6;
    const int n0 = blockIdx.x * 256;
    const int nend = min(n0 + 256, N);
    float rmax = 0.f, rsum = 0.f;
    int curG = -1, cnt = 0;
    for (int n = n0 + w; n < nend; n += 4){
        int g = batch[n];
        float v = h[(size_t)n * 64 + lane];
        if (g != curG){
            if (curG >= 0){
                atomicMax((int*)&gmx[curG * 64 + lane], __float_as_int(rmax));
                atomicAdd(&gsum[curG * 64 + lane], rsum);
                if (lane == 0) atomicAdd(&gcnt[curG], cnt);
            }
            curG = g; rmax = v; rsum = v; cnt = 1;
        } else {
            rmax = fmaxf(rmax, v); rsum += v; ++cnt;
        }
    }
    if (curG >= 0){
        atomicMax((int*)&gmx[curG * 64 + lane], __float_as_int(rmax));
        atomicAdd(&gsum[curG * 64 + lane], rsum);
        if (lane == 0) atomicAdd(&gcnt[curG], cnt);
    }
}

__global__ __launch_bounds__(640)
void final_linear(const float* __restrict__ gmx, const float* __restrict__ gsum,
                  const int* __restrict__ gcnt,
                  const float* __restrict__ Wout, const float* __restrict__ bout,
                  float* __restrict__ out){
    __shared__ float sg[4096], ss[4096];
    int t = threadIdx.x;
    for (int i = t; i < 4096; i += 640){ sg[i] = gmx[i]; ss[i] = gsum[i]; }
    __syncthreads();
    int g = t / 10, oc = t % 10;
    float icnt = 1.f / (float)max(gcnt[g], 1);
    float acc = bout[oc], accs = 0.f;
    #pragma unroll 4
    for (int k = 0; k < 64; ++k) acc  += sg[g * 64 + k] * Wout[k * 10 + oc];
    #pragma unroll 4
    for (int k = 0; k < 64; ++k) accs += ss[g * 64 + k] * Wout[(64 + k) * 10 + oc];
    out[g * 10 + oc] = acc + accs * icnt;
}

// ---------------- launch ----------------
extern "C" void kernel_launch(void* const* d_in, const int* in_sizes, int n_in,
                              void* d_out, int out_size, void* d_ws, size_t ws_size,
                              hipStream_t stream){
    const int N = 50000, E = 800000, B = 64;
    const float* x    = (const float*)d_in[0];
    const int*  ei    = (const int*)d_in[1];
    const int*  batch = (const int*)d_in[2];
    const float *Wl0=(const float*)d_in[3],  *bl0=(const float*)d_in[4],
                *Wr0=(const float*)d_in[5],  *br0=(const float*)d_in[6],
                *att0=(const float*)d_in[7], *bias0=(const float*)d_in[8];
    const float *Wl1=(const float*)d_in[9],  *bl1=(const float*)d_in[10],
                *Wr1=(const float*)d_in[11], *br1=(const float*)d_in[12],
                *att1=(const float*)d_in[13],*bias1=(const float*)d_in[14];
    const float *Wl2=(const float*)d_in[15], *bl2=(const float*)d_in[16],
                *Wr2=(const float*)d_in[17], *br2=(const float*)d_in[18],
                *att2=(const float*)d_in[19],*bias2=(const float*)d_in[20];
    const float *Wout=(const float*)d_in[21],*bout=(const float*)d_in[22];

    const int* srcA = ei;
    const int* dstA = ei + E;

    char* p = (char*)d_ws;
    auto alloc = [&](size_t bytes)->void*{ void* r = (void*)p; p += (bytes + 255) & ~(size_t)255; return r; };
    void*  bufA   = alloc((size_t)N * 192 * 4);                 // h: bf16 (L0,L1) / f32 (L2)
    float* bufC   = (float*)alloc((size_t)N * 192 * 4);         // xr (f32)
    unsigned short* xlb = (unsigned short*)alloc((size_t)N * 192 * 2); // xl (bf16)
    unsigned short* WT0 = (unsigned short*)alloc((size_t)384 * 32 * 2);
    unsigned short* WT1 = (unsigned short*)alloc((size_t)256 * 192 * 2);
    unsigned short* WT2 = (unsigned short*)alloc((size_t)256 * 128 * 2);
    int* counts   = (int*)alloc((size_t)N * 4);
    int* offsets  = (int*)alloc((size_t)N * 4);
    int* cursor   = (int*)alloc((size_t)N * 4);
    int* blockSums= (int*)alloc(256 * 4);
    const size_t EBB = ((size_t)(E + 24) * 4 + 255) & ~(size_t)255;  // rounded slab
    int* eb384    = (int*)alloc((size_t)(E + 24) * 4);
    int* eb256    = (int*)alloc((size_t)(E + 24) * 4);               // contiguous after eb384
    float* pool   = (float*)alloc((size_t)(B * 128 + B) * 4);   // gmx | gsum | gcnt
    float* gmx  = pool;
    float* gsum = pool + B * 64;
    int*   gcnt = (int*)(pool + B * 128);

    // weight transpose + bf16 (one dispatch)
    build_wt_all<<<(94208 + 255) / 256, 256, 0, stream>>>(Wl0, Wr0, Wl1, Wr1, Wl2, Wr2, WT0, WT1, WT2);

    // CSR build (reused by all 3 layers)
    hipMemsetAsync(counts, 0, (size_t)N * 4, stream);
    // FULL zero of both offset arrays (one dispatch — they are contiguous):
    // self-loop edges leave an E'..E gap that the aggregation prefetch reads
    // (r8/r9 fault: 0xAA poison -> OOB deref).
    hipMemsetAsync(eb384, 0, EBB * 2, stream);
    int eb = (E + 255) / 256;
    int nb = (N + 255) / 256;
    edge_count<<<eb, 256, 0, stream>>>(srcA, dstA, E, counts);
    scan_block<<<nb, 256, 0, stream>>>(counts, offsets, blockSums, N);
    scan_sums<<<1, 256, 0, stream>>>(blockSums, nb);
    scan_add<<<nb, 256, 0, stream>>>(offsets, cursor, blockSums, N);
    edge_scatter<<<eb, 256, 0, stream>>>(srcA, dstA, E, cursor, eb384, eb256);

    const int rb = (N + 63) / 64;   // 64-row tiles
    const int ab = (N + 3) / 4;     // agg blocks: one wave per node

    // layer 0: 32 -> 192 (H=3, C=64), concat; h0 out bf16
    mfma_dual_linear<32, 384, 192, false><<<rb, 256, 0, stream>>>(x, WT0, bl0, br0, xlb, bufC, N);
    gatv2_agg<3, false, true><<<ab, 256, 0, stream>>>(xlb, bufC, att0, bias0, offsets, counts, eb384, bufA, N);

    // layer 1: 192 -> 128 (H=2), concat; h1 out bf16
    mfma_dual_linear<192, 256, 128, true><<<rb, 256, 0, stream>>>(bufA, WT1, bl1, br1, xlb, bufC, N);
    gatv2_agg<2, false, true><<<ab, 256, 0, stream>>>(xlb, bufC, att1, bias1, offsets, counts, eb256, bufA, N);

    // layer 2: 128 -> 128 (H=2), mean over heads -> 64; out f32 for pooling
    mfma_dual_linear<128, 256, 128, true><<<rb, 256, 0, stream>>>(bufA, WT2, bl2, br2, xlb, bufC, N);
    gatv2_agg<2, true, false><<<ab, 256, 0, stream>>>(xlb, bufC, att2, bias2, offsets, counts, eb256, bufA, N);

    // pooling + output linear
    hipMemsetAsync(pool, 0, (size_t)(B * 128 + B) * 4, stream);
    pool_kernel<<<(N + 255) / 256, 256, 0, stream>>>((const float*)bufA, batch, N, gmx, gsum, gcnt);
    final_linear<<<1, 640, 0, stream>>>(gmx, gsum, gcnt, Wout, bout, (float*)d_out);
}